// Round 12
// baseline (396.621 us; speedup 1.0000x reference)
//
#include <hip/hip_runtime.h>

// LQR KKT solve via backward Riccati recursion + forward rollout.
// T=128, n_state=16, n_ctrl=8, n_all=24. Single block, 256 threads.
// Base: proven R9 (320us, absmax 0.002). SINGLE structural delta:
//   backward step collapsed 5 -> 3 barrier phases. The two GJ rounds and
//   the update phase merge into ONE phase: every lane solves H x = col_j
//   of [G|rhs] fully in registers (H broadcast-read as 16x float4;
//   unrolled pivot-free LU -- H SPD >= I so dets >= 1, proven since R6),
//   then applies the P/F/p/d updates immediately (R9 phase-5 algebra,
//   kc[] register-resident, all indices static per rule #20).
// Barriers: builtin __syncthreads() ONLY (R10/R11 proved asm barriers and
// sched_barrier regress). Gu dual-write remains banned (R3-R5).
// mu_t = P_t x_t + p_t (stable). Forward pass identical to R9.
// d_ws: Pws[T*256] | pws[T*16] | Fws[T*256] | dws[T*16].

constexpr int T  = 128;
constexpr int NA = 24;

// 16-elem dot: LDS float4 stream x register-resident row.
__device__ __forceinline__ float dot16r(const float* lds, const float* r, float s) {
    const float4* a4 = (const float4*)lds;
#pragma unroll
    for (int q = 0; q < 4; ++q) {
        float4 x = a4[q];
        s = fmaf(x.x, r[4 * q + 0], s); s = fmaf(x.y, r[4 * q + 1], s);
        s = fmaf(x.z, r[4 * q + 2], s); s = fmaf(x.w, r[4 * q + 3], s);
    }
    return s;
}
// 16-elem dot: both operands LDS float4.
__device__ __forceinline__ float dot16f4(const float* a, const float* b, float s) {
    const float4* a4 = (const float4*)a;
    const float4* b4 = (const float4*)b;
#pragma unroll
    for (int q = 0; q < 4; ++q) {
        float4 x = a4[q], y = b4[q];
        s = fmaf(x.x, y.x, s); s = fmaf(x.y, y.y, s);
        s = fmaf(x.z, y.z, s); s = fmaf(x.w, y.w, s);
    }
    return s;
}

__global__ __launch_bounds__(256, 1)
void lqr_solve(const float* __restrict__ gA,
               const float* __restrict__ gB,
               const float* __restrict__ gx0,
               const float* __restrict__ gC,
               const float* __restrict__ gc,
               float* __restrict__ out,
               float* __restrict__ Pws,   // [T*256] P_t row-major
               float* __restrict__ pws,   // [T*16]  p_t
               float* __restrict__ Fws,   // [T*256] F_t = A - B K_t
               float* __restrict__ dws)   // [T*16]  d_t = -B k_t
{
    __shared__ __align__(16) float A_sh[16][16];
    __shared__ __align__(16) float At_sh[16][16];
    __shared__ __align__(16) float B_sh[16][8];
    __shared__ __align__(16) float Bt_sh[8][16];
    __shared__ __align__(16) float P_sh[2][16][20];
    __shared__ __align__(16) float p_sh[2][16];
    __shared__ __align__(16) float Wt[16][20];
    __shared__ __align__(16) float Vt[8][20];
    __shared__ __align__(16) float Gu[16][8];
    __shared__ __align__(16) float Aug[8][28];   // single buffer: [H|G|rhs]
    __shared__ __align__(16) float Kall[T][8][16];
    __shared__ __align__(16) float kall[T][8];
    __shared__ __align__(16) float c_sh[T][NA];
    __shared__ __align__(16) float z_sh[T][NA];
    __shared__ __align__(16) float Csh[2][24][25];

    const int tid = threadIdx.x;

    // ---- init staging (identical to R9) ----
    {
        const int i = tid >> 4, j = tid & 15;
        const float v = gA[tid];
        A_sh[i][j] = v; At_sh[j][i] = v;
        P_sh[0][i][j] = 0.0f;
        if (j < 4) P_sh[0][i][16 + j] = 0.0f;
    }
    if (tid < 128) {
        const int i = tid >> 3, j = tid & 7;
        const float v = gB[tid];
        B_sh[i][j] = v; Bt_sh[j][i] = v;
    }
    if (tid < 16) p_sh[0][tid] = 0.0f;
    for (int idx = tid; idx < T * NA; idx += 256) c_sh[idx / NA][idx % NA] = gc[idx];
    for (int idx = tid; idx < 576; idx += 256)
        Csh[0][idx / 24][idx % 24] = gC[(T - 1) * 576 + idx];
    __syncthreads();

    // ---- per-lane register caches of invariant rows ----
    float atr[16], btr_e[16], btr3[16], atr2[16], brow[8], browp[8];
    {
        const int rA  = tid >> 4;
        const int rBe = (tid >> 4) & 7;
        const int rB3 = (tid / 25) & 7;
        const int rA2 = (tid >> 3) & 15;
        const int rBp = tid & 15;
#pragma unroll
        for (int q = 0; q < 4; ++q) {
            float4 v;
            v = *(const float4*)&At_sh[rA][4 * q];
            atr[4*q]=v.x; atr[4*q+1]=v.y; atr[4*q+2]=v.z; atr[4*q+3]=v.w;
            v = *(const float4*)&Bt_sh[rBe][4 * q];
            btr_e[4*q]=v.x; btr_e[4*q+1]=v.y; btr_e[4*q+2]=v.z; btr_e[4*q+3]=v.w;
            v = *(const float4*)&Bt_sh[rB3][4 * q];
            btr3[4*q]=v.x; btr3[4*q+1]=v.y; btr3[4*q+2]=v.z; btr3[4*q+3]=v.w;
            v = *(const float4*)&At_sh[rA2][4 * q];
            atr2[4*q]=v.x; atr2[4*q+1]=v.y; atr2[4*q+2]=v.z; atr2[4*q+3]=v.w;
        }
#pragma unroll
        for (int q = 0; q < 2; ++q) {
            float4 v;
            v = *(const float4*)&B_sh[rA][4 * q];
            brow[4*q]=v.x; brow[4*q+1]=v.y; brow[4*q+2]=v.z; brow[4*q+3]=v.w;
            v = *(const float4*)&B_sh[rBp][4 * q];
            browp[4*q]=v.x; browp[4*q+1]=v.y; browp[4*q+2]=v.z; browp[4*q+3]=v.w;
        }
    }

    // ---- backward Riccati: 3 phases per step ----
    int pb = 0;
    for (int t = T - 1; t >= 0; --t) {
        const int cb = (T - 1 - t) & 1;

        float pf0 = 0.f, pf1 = 0.f, pf2 = 0.f;
        if (t > 0) {
            const float* src = gC + (size_t)(t - 1) * 576;
            pf0 = src[tid];
            pf1 = src[tid + 256];
            if (tid < 64) pf2 = src[tid + 512];
        }

        // phase A: Wt = (P'A)^T, Vt = (P'B)^T
        {
            const int j = tid >> 4, k = tid & 15;
            Wt[j][k] = dot16r(&P_sh[pb][k][0], atr, 0.0f);
            if (tid < 128) {
                Vt[j][k] = dot16r(&P_sh[pb][k][0], btr_e, 0.0f);
            }
        }
        __syncthreads();

        // phase B: Aug = [H | G | rhs] and Gu = S + A^T P' B
        if (tid < 200) {
            const int i = tid / 25, j = tid % 25;
            float s;
            if (j < 8) {
                s = dot16r(&Vt[j][0], btr3, Csh[cb][16 + i][16 + j]);
            } else if (j < 24) {
                const int jj = j - 8;
                s = dot16r(&Wt[jj][0], btr3, Csh[cb][16 + i][jj]);
            } else {
                s = dot16r(&p_sh[pb][0], btr3, c_sh[t][16 + i]);
            }
            Aug[i][j] = s;
        }
        if (tid < 128) {
            const int i = tid >> 3, j = tid & 7;
            Gu[i][j] = dot16r(&Vt[j][0], atr2, Csh[cb][i][16 + j]);
        }
        __syncthreads();

        // phase C (merged solve + updates):
        // every lane solves H x = [G col j | rhs] in registers, then updates.
        {
            const int i = tid >> 4, j = tid & 15;
            // H: broadcast float4 reads (identical addresses across lanes)
            float h[8][8];
#pragma unroll
            for (int y = 0; y < 8; ++y) {
                const float4 a = *(const float4*)&Aug[y][0];
                const float4 b = *(const float4*)&Aug[y][4];
                h[y][0]=a.x; h[y][1]=a.y; h[y][2]=a.z; h[y][3]=a.w;
                h[y][4]=b.x; h[y][5]=b.y; h[y][6]=b.z; h[y][7]=b.w;
            }
            // g = G column j ; g2 = rhs column (uniform; used by lanes<16)
            float g[8], g2[8];
#pragma unroll
            for (int y = 0; y < 8; ++y) { g[y] = Aug[y][8 + j]; g2[y] = Aug[y][24]; }
            // pivot-free LU (H SPD >= I): forward elimination, unit-U rows
#pragma unroll
            for (int p = 0; p < 8; ++p) {
                const float rp = 1.0f / h[p][p];
#pragma unroll
                for (int c = p + 1; c < 8; ++c) h[p][c] *= rp;
                g[p] *= rp; g2[p] *= rp;
#pragma unroll
                for (int r = p + 1; r < 8; ++r) {
                    const float f = h[r][p];
#pragma unroll
                    for (int c = p + 1; c < 8; ++c)
                        h[r][c] = fmaf(-f, h[p][c], h[r][c]);
                    g[r]  = fmaf(-f, g[p],  g[r]);
                    g2[r] = fmaf(-f, g2[p], g2[r]);
                }
            }
            // back substitution (U has unit diagonal)
#pragma unroll
            for (int p = 6; p >= 0; --p) {
                float s = g[p], s2 = g2[p];
#pragma unroll
                for (int c = p + 1; c < 8; ++c) {
                    s  = fmaf(-h[p][c], g[c],  s);
                    s2 = fmaf(-h[p][c], g2[c], s2);
                }
                g[p] = s; g2[p] = s2;
            }
            // g[y] = K[y][j], g2[y] = k[y]

            // exports (static indices only)
            if (i == 0) {
                Kall[t][0][j] = g[0]; Kall[t][1][j] = g[1];
                Kall[t][2][j] = g[2]; Kall[t][3][j] = g[3];
                Kall[t][4][j] = g[4]; Kall[t][5][j] = g[5];
                Kall[t][6][j] = g[6]; Kall[t][7][j] = g[7];
            }
            if (tid == 0) {
                kall[t][0] = g2[0]; kall[t][1] = g2[1];
                kall[t][2] = g2[2]; kall[t][3] = g2[3];
                kall[t][4] = g2[4]; kall[t][5] = g2[5];
                kall[t][6] = g2[6]; kall[t][7] = g2[7];
            }

            // P-update: P = Q + A^T W - Gu K ; F = A - B K
            float s = dot16r(&Wt[j][0], atr, Csh[cb][i][j]);
            float s2 = 0.f, fa = 0.f;
            const float4 g0 = *(const float4*)&Gu[i][0];
            const float4 g1 = *(const float4*)&Gu[i][4];
            s2 = fmaf(g0.x, g[0], s2); s2 = fmaf(g0.y, g[1], s2);
            s2 = fmaf(g0.z, g[2], s2); s2 = fmaf(g0.w, g[3], s2);
            s2 = fmaf(g1.x, g[4], s2); s2 = fmaf(g1.y, g[5], s2);
            s2 = fmaf(g1.z, g[6], s2); s2 = fmaf(g1.w, g[7], s2);
#pragma unroll
            for (int y = 0; y < 8; ++y) fa = fmaf(brow[y], g[y], fa);
            const float v = s - s2;
            P_sh[pb ^ 1][i][j] = v;
            Pws[t * 256 + tid] = v;
            Fws[t * 256 + tid] = A_sh[i][j] - fa;

            // p-update lanes (tid < 16) use g2 = k
            if (tid < 16) {
                float sp = dot16f4(&At_sh[tid][0], &p_sh[pb][0], c_sh[t][tid]);
                float sp2 = 0.f, da = 0.f;
#pragma unroll
                for (int q = 0; q < 8; ++q) {
                    sp2 = fmaf(Gu[tid][q], g2[q], sp2);
                    da  = fmaf(browp[q],  g2[q], da);
                }
                const float vp = sp - sp2;
                p_sh[pb ^ 1][tid] = vp;
                pws[t * 16 + tid] = vp;
                dws[t * 16 + tid] = -da;
            }
        }
        if (t > 0) {
            Csh[cb ^ 1][tid / 24][tid % 24] = pf0;
            Csh[cb ^ 1][(tid + 256) / 24][(tid + 256) % 24] = pf1;
            if (tid < 64) Csh[cb ^ 1][(tid + 512) / 24][(tid + 512) % 24] = pf2;
        }
        __syncthreads();
        pb ^= 1;
    }

    // ws stores complete before forward-pass reads (R9 boundary)
    __syncthreads();
    asm volatile("s_waitcnt vmcnt(0)" ::: "memory");

    // ---- forward rollout: one phase per step (identical to R9) ----
    if (tid < 16) z_sh[0][tid] = gx0[tid];
    float fcur[16], dcur = 0.f, prow[16], pcur = 0.f;
    if (tid < 16) {
#pragma unroll
        for (int q = 0; q < 4; ++q) {
            float4 v = *(const float4*)&Fws[tid * 16 + 4 * q];
            fcur[4*q]=v.x; fcur[4*q+1]=v.y; fcur[4*q+2]=v.z; fcur[4*q+3]=v.w;
        }
        dcur = dws[tid];
    }
    if (tid >= 32 && tid < 48) {
        const int i = tid - 32;
#pragma unroll
        for (int q = 0; q < 4; ++q) {
            float4 v = *(const float4*)&Pws[i * 16 + 4 * q];
            prow[4*q]=v.x; prow[4*q+1]=v.y; prow[4*q+2]=v.z; prow[4*q+3]=v.w;
        }
        pcur = pws[i];
    }
    __syncthreads();
    for (int t = 0; t < T; ++t) {
        float fn[16], dn = 0.f, pn[16], ppn = 0.f;
        if (t < T - 1) {
            if (tid < 16) {
#pragma unroll
                for (int q = 0; q < 4; ++q) {
                    float4 v = *(const float4*)&Fws[(t + 1) * 256 + tid * 16 + 4 * q];
                    fn[4*q]=v.x; fn[4*q+1]=v.y; fn[4*q+2]=v.z; fn[4*q+3]=v.w;
                }
                dn = dws[(t + 1) * 16 + tid];
            }
            if (tid >= 32 && tid < 48) {
                const int i = tid - 32;
#pragma unroll
                for (int q = 0; q < 4; ++q) {
                    float4 v = *(const float4*)&Pws[(t + 1) * 256 + i * 16 + 4 * q];
                    pn[4*q]=v.x; pn[4*q+1]=v.y; pn[4*q+2]=v.z; pn[4*q+3]=v.w;
                }
                ppn = pws[(t + 1) * 16 + i];
            }
        }
        if (tid >= 16 && tid < 24) {        // u_t = -(K_t x_t + k_t)
            const int y = tid - 16;
            float s = dot16f4(&Kall[t][y][0], &z_sh[t][0], kall[t][y]);
            z_sh[t][16 + y] = -s;
        }
        if (tid >= 32 && tid < 48) {        // mu_t = +/- (P_t x_t + p_t)
            const int i = tid - 32;
            float s = pcur;
            const float4* zr = (const float4*)&z_sh[t][0];
#pragma unroll
            for (int q = 0; q < 4; ++q) {
                float4 z = zr[q];
                s = fmaf(prow[4*q+0], z.x, s); s = fmaf(prow[4*q+1], z.y, s);
                s = fmaf(prow[4*q+2], z.z, s); s = fmaf(prow[4*q+3], z.w, s);
            }
            if (t == 0) s = -s;
            out[T * NA + t * 16 + i] = s;
        }
        if (t < T - 1 && tid < 16) {        // x_{t+1} = F_t x_t + d_t
            const float4* zr = (const float4*)&z_sh[t][0];
            float s = dcur;
#pragma unroll
            for (int q = 0; q < 4; ++q) {
                float4 z = zr[q];
                s = fmaf(fcur[4*q+0], z.x, s); s = fmaf(fcur[4*q+1], z.y, s);
                s = fmaf(fcur[4*q+2], z.z, s); s = fmaf(fcur[4*q+3], z.w, s);
            }
            z_sh[t + 1][tid] = s;
        }
        __syncthreads();
        if (t < T - 1) {
            if (tid < 16) {
#pragma unroll
                for (int q = 0; q < 16; ++q) fcur[q] = fn[q];
                dcur = dn;
            }
            if (tid >= 32 && tid < 48) {
#pragma unroll
                for (int q = 0; q < 16; ++q) prow[q] = pn[q];
                pcur = ppn;
            }
        }
    }

    // ---- write z ----
    for (int idx = tid; idx < T * NA; idx += 256)
        out[idx] = z_sh[idx / 24][idx % 24];
}

extern "C" void kernel_launch(void* const* d_in, const int* in_sizes, int n_in,
                              void* d_out, int out_size, void* d_ws, size_t ws_size,
                              hipStream_t stream) {
    const float* gA  = (const float*)d_in[0];
    const float* gB  = (const float*)d_in[1];
    const float* gx0 = (const float*)d_in[2];
    const float* gC  = (const float*)d_in[3];
    const float* gc  = (const float*)d_in[4];
    float* out = (float*)d_out;
    float* Pws = (float*)d_ws;           // T*256 floats
    float* pws = Pws + T * 256;          // T*16
    float* Fws = pws + T * 16;           // T*256
    float* dws = Fws + T * 256;          // T*16
    lqr_solve<<<dim3(1), dim3(256), 0, stream>>>(gA, gB, gx0, gC, gc, out,
                                                 Pws, pws, Fws, dws);
}